// Round 3
// baseline (208.449 us; speedup 1.0000x reference)
//
#include <hip/hip_runtime.h>

#define NCLS 512
#define DIM 512
#define D4 128            // float4 per row
#define NCHUNK 32         // 32 column chunks x 16 f32 = 512 cols
#define WPAD 17           // padded LDS row (16 f32 + 1)
#define EPS 1e-6f
#define MARGIN 1.0f

// Kernel 0: zero the accumulators we atomically add into.
__global__ __launch_bounds__(512)
void k_init(int* __restrict__ cnts, float* __restrict__ total, float* __restrict__ d_out)
{
    const int t = threadIdx.x;
    if (t < NCLS) { cnts[t] = 0; total[t] = 0.f; }
    if (t == 0) d_out[0] = 0.f;
}

// Kernel 1: label histogram (LDS-private per block, then global atomics).
__global__ __launch_bounds__(256)
void k_hist(const int* __restrict__ lab, int* __restrict__ cnts, int N)
{
    __shared__ int h[NCLS];
    const int t = threadIdx.x;
    h[t] = 0; h[t + 256] = 0;
    __syncthreads();

    const int4* lab4 = (const int4*)lab;
    const int nv = N >> 2;
    for (int j = blockIdx.x * 256 + t; j < nv; j += gridDim.x * 256) {
        const int4 l = lab4[j];
        atomicAdd(&h[l.x], 1);
        atomicAdd(&h[l.y], 1);
        atomicAdd(&h[l.z], 1);
        atomicAdd(&h[l.w], 1);
    }
    __syncthreads();
    if (h[t])       atomicAdd(&cnts[t], h[t]);
    if (h[t + 256]) atomicAdd(&cnts[t + 256], h[t + 256]);
}

// Kernel 2: the main pass. Sequential streaming of x; scatter into LDS hist.
// Grid: NCHUNK * nrr blocks; block (w, rr) covers column chunk w (16 f32)
// of rows [rr*rows_per_rr, (rr+1)*rows_per_rr). Flush to partials[rr][c][d].
__global__ __launch_bounds__(512)
void k_stream(const float4* __restrict__ x4, const int* __restrict__ lab,
              float* __restrict__ partials, int rows_per_rr)
{
    __shared__ float h[NCLS * WPAD];
    const int t  = threadIdx.x;
    const int w  = blockIdx.x & (NCHUNK - 1);
    const int rr = blockIdx.x >> 5;

    for (int i = t; i < NCLS * WPAD; i += 512) h[i] = 0.f;
    __syncthreads();

    const int q    = t & 3;    // float4 within the 16-f32 chunk
    const int rsub = t >> 2;   // 0..127: row-quad id
    const int row0 = rr * rows_per_rr;
    const int col4 = w * 4 + q;

    // 512 rows per macro-step: each thread owns 4 consecutive rows.
    for (int s = 0; s < rows_per_rr; s += 512) {
        const int r = row0 + s + rsub * 4;
        const int4   lc = *(const int4*)&lab[r];
        const float4 v0 = x4[(size_t)(r + 0) * D4 + col4];
        const float4 v1 = x4[(size_t)(r + 1) * D4 + col4];
        const float4 v2 = x4[(size_t)(r + 2) * D4 + col4];
        const float4 v3 = x4[(size_t)(r + 3) * D4 + col4];

        float* b0 = &h[lc.x * WPAD + q * 4];
        atomicAdd(b0 + 0, v0.x); atomicAdd(b0 + 1, v0.y);
        atomicAdd(b0 + 2, v0.z); atomicAdd(b0 + 3, v0.w);
        float* b1 = &h[lc.y * WPAD + q * 4];
        atomicAdd(b1 + 0, v1.x); atomicAdd(b1 + 1, v1.y);
        atomicAdd(b1 + 2, v1.z); atomicAdd(b1 + 3, v1.w);
        float* b2 = &h[lc.z * WPAD + q * 4];
        atomicAdd(b2 + 0, v2.x); atomicAdd(b2 + 1, v2.y);
        atomicAdd(b2 + 2, v2.z); atomicAdd(b2 + 3, v2.w);
        float* b3 = &h[lc.w * WPAD + q * 4];
        atomicAdd(b3 + 0, v3.x); atomicAdd(b3 + 1, v3.y);
        atomicAdd(b3 + 2, v3.z); atomicAdd(b3 + 3, v3.w);
    }
    __syncthreads();

    // Flush LDS -> partials[rr][c][w*16 + col], coalesced (16 lanes per class).
    const int col = t & 15;
    const int csub = t >> 4;   // 0..31
    for (int cg = 0; cg < 16; ++cg) {
        const int c = cg * 32 + csub;
        partials[((size_t)rr * NCLS + c) * DIM + w * 16 + col] = h[c * WPAD + col];
    }
}

// Kernel 3: reduce partials over row-ranges; also build total[] atomically.
__global__ __launch_bounds__(512)
void k_reduce(const float* __restrict__ partials, int nrr,
              float* __restrict__ cls_sums, float* __restrict__ total)
{
    const int c = blockIdx.x;
    const int d = threadIdx.x;
    float s = 0.f;
    for (int rr = 0; rr < nrr; ++rr)
        s += partials[((size_t)rr * NCLS + c) * DIM + d];
    cls_sums[(size_t)c * DIM + d] = s;
    atomicAdd(&total[d], s);
}

// Kernel 4: per class, d_c = ||s/c - (total-s)/(N-c) + eps||; accumulate loss.
__global__ __launch_bounds__(256)
void k_finalize(const float* __restrict__ cls_sums, const int* __restrict__ cnts,
                const float* __restrict__ total, float* __restrict__ d_out, int N)
{
    const int c   = blockIdx.x;
    const int tid = threadIdx.x;
    const int cnt = cnts[c];

    const float2 s = ((const float2*)cls_sums)[c * (DIM / 2) + tid];
    const float2 t = ((const float2*)total)[tid];

    float ss = 0.f;
    if (cnt > 0) {
        const float inv_c  = 1.f / (float)cnt;
        const float inv_nc = 1.f / (float)(N - cnt);
        const float d0 = s.x * inv_c - (t.x - s.x) * inv_nc + EPS;
        const float d1 = s.y * inv_c - (t.y - s.y) * inv_nc + EPS;
        ss = d0 * d0 + d1 * d1;
    }

    #pragma unroll
    for (int o = 1; o < 64; o <<= 1) ss += __shfl_xor(ss, o, 64);

    __shared__ float s_red[4];
    if ((tid & 63) == 0) s_red[tid >> 6] = ss;
    __syncthreads();

    if (tid == 0) {
        const float tot = (s_red[0] + s_red[1]) + (s_red[2] + s_red[3]);
        const float d = sqrtf(tot);
        const float w = fmaxf(MARGIN - d, 0.f);
        if (cnt > 0) atomicAdd(d_out, (float)cnt * w * w / (float)N);
    }
}

extern "C" void kernel_launch(void* const* d_in, const int* in_sizes, int n_in,
                              void* d_out, int out_size, void* d_ws, size_t ws_size,
                              hipStream_t stream)
{
    const float* x   = (const float*)d_in[0];
    const int*   lab = (const int*)d_in[1];
    float*       out = (float*)d_out;

    const int N = in_sizes[1];  // 65536 samples

    // Pick number of row-ranges (power of 2) that fits the workspace:
    // need nrr * 1 MB (partials) + ~1.1 MB (cls_sums/total/cnts).
    const size_t fixed = (size_t)(NCLS * DIM + DIM + NCLS) * 4 + 256;
    int nrr = 16;
    while (nrr > 1 && ((size_t)nrr * NCLS * DIM * 4 + fixed > ws_size || (N % nrr) != 0))
        nrr >>= 1;
    const int rows_per_rr = N / nrr;  // must also be a multiple of 512 (N=65536: yes)

    float* partials = (float*)d_ws;                            // nrr*NCLS*DIM f32
    float* cls_sums = partials + (size_t)nrr * NCLS * DIM;     // NCLS*DIM
    float* total    = cls_sums + (size_t)NCLS * DIM;           // DIM
    int*   cnts     = (int*)(total + DIM);                     // NCLS

    k_init<<<1, 512, 0, stream>>>(cnts, total, out);
    k_hist<<<64, 256, 0, stream>>>(lab, cnts, N);
    k_stream<<<NCHUNK * nrr, 512, 0, stream>>>((const float4*)x, lab, partials, rows_per_rr);
    k_reduce<<<NCLS, 512, 0, stream>>>(partials, nrr, cls_sums, total);
    k_finalize<<<NCLS, 256, 0, stream>>>(cls_sums, cnts, total, out, N);
}

// Round 4
// 73.043 us; speedup vs baseline: 2.8538x; 2.8538x over previous
//
#include <hip/hip_runtime.h>

#define NCLS 512
#define DIM 512
#define D4 128            // float4 per row
#define EPS 1e-6f
#define MARGIN 1.0f

// ---------------- Kernel 0: zero cnts ----------------
__global__ __launch_bounds__(512)
void k_init(int* __restrict__ cnts)
{
    cnts[threadIdx.x] = 0;
}

// ---------------- Kernel 1: label histogram ----------------
__global__ __launch_bounds__(256)
void k_hist(const int* __restrict__ lab, int* __restrict__ cnts, int N)
{
    __shared__ int h[NCLS];
    const int t = threadIdx.x;
    h[t] = 0; h[t + 256] = 0;
    __syncthreads();

    const int4* lab4 = (const int4*)lab;
    const int nv = N >> 2;
    for (int j = blockIdx.x * 256 + t; j < nv; j += gridDim.x * 256) {
        const int4 l = lab4[j];
        atomicAdd(&h[l.x], 1);
        atomicAdd(&h[l.y], 1);
        atomicAdd(&h[l.z], 1);
        atomicAdd(&h[l.w], 1);
    }
    __syncthreads();
    if (h[t])       atomicAdd(&cnts[t], h[t]);
    if (h[t + 256]) atomicAdd(&cnts[t + 256], h[t + 256]);
}

// ---------------- Kernel 2: exclusive scan over 512 counts ----------------
__global__ __launch_bounds__(512)
void k_scan(const int* __restrict__ cnts, int* __restrict__ offsets,
            int* __restrict__ cur, float* __restrict__ d_out)
{
    __shared__ int h[NCLS];
    const int t = threadIdx.x;
    const int myc = cnts[t];
    h[t] = myc;
    __syncthreads();
    for (int o = 1; o < NCLS; o <<= 1) {
        const int add = (t >= o) ? h[t - o] : 0;
        __syncthreads();
        h[t] += add;
        __syncthreads();
    }
    offsets[t] = h[t] - myc;
    cur[t]     = h[t] - myc;
    if (t == 0) d_out[0] = 0.f;
}

// ---------------- Kernel 3: scatter indices into class order ----------------
__global__ __launch_bounds__(256)
void k_scatter(const int* __restrict__ lab, int* __restrict__ cur,
               int* __restrict__ sorted, int N)
{
    int i = blockIdx.x * blockDim.x + threadIdx.x;
    const int stride = gridDim.x * blockDim.x;
    for (; i < N; i += stride) {
        const int c = lab[i];
        const int p = atomicAdd(&cur[c], 1);
        sorted[p] = i;
    }
}

// ---------------- Kernel 4: per-class gather-sum, MLP-deep ----------------
// One block per class, 512 threads: (col4 = t&127, rquad = t>>7).
// Indices staged in LDS; 4 independent float4 loads in flight per thread.
__global__ __launch_bounds__(512)
void k_gather(const float4* __restrict__ x4, const int* __restrict__ sorted,
              const int* __restrict__ offsets, const int* __restrict__ cnts,
              float4* __restrict__ cls_sums4)
{
    const int c    = blockIdx.x;
    const int t    = threadIdx.x;
    const int col4 = t & 127;
    const int rq   = t >> 7;     // 0..3
    const int off  = offsets[c];
    const int cnt  = cnts[c];

    __shared__ int    s_idx[512];
    __shared__ float4 s_red[512];

    float4 acc = make_float4(0.f, 0.f, 0.f, 0.f);

    for (int done = 0; done < cnt; done += 512) {
        const int chunk = min(cnt - done, 512);
        if (t < chunk) s_idx[t] = sorted[off + done + t];
        __syncthreads();

        int base = 0;
        for (; base + 16 <= chunk; base += 16) {
            const int i0 = s_idx[base + rq];
            const int i1 = s_idx[base + 4 + rq];
            const int i2 = s_idx[base + 8 + rq];
            const int i3 = s_idx[base + 12 + rq];
            const float4 v0 = x4[(size_t)i0 * D4 + col4];
            const float4 v1 = x4[(size_t)i1 * D4 + col4];
            const float4 v2 = x4[(size_t)i2 * D4 + col4];
            const float4 v3 = x4[(size_t)i3 * D4 + col4];
            acc.x += (v0.x + v1.x) + (v2.x + v3.x);
            acc.y += (v0.y + v1.y) + (v2.y + v3.y);
            acc.z += (v0.z + v1.z) + (v2.z + v3.z);
            acc.w += (v0.w + v1.w) + (v2.w + v3.w);
        }
        for (; base + rq < chunk; base += 4) {
            const int i = s_idx[base + rq];
            const float4 v = x4[(size_t)i * D4 + col4];
            acc.x += v.x; acc.y += v.y; acc.z += v.z; acc.w += v.w;
        }
        __syncthreads();   // protect s_idx before next chunk
    }

    s_red[t] = acc;
    __syncthreads();
    if (t < 128) {
        float4 s = s_red[t];
        const float4 a = s_red[t + 128];
        const float4 b = s_red[t + 256];
        const float4 d = s_red[t + 384];
        s.x += (a.x + b.x) + d.x;
        s.y += (a.y + b.y) + d.y;
        s.z += (a.z + b.z) + d.z;
        s.w += (a.w + b.w) + d.w;
        cls_sums4[(size_t)c * D4 + t] = s;
    }
}

// ---------------- Kernel 5: total[d] = sum_c cls_sums[c][d] ----------------
// 4 blocks x 128 threads; block covers 32 float4 cols, 4 class-groups reduce.
__global__ __launch_bounds__(128)
void k_total(const float4* __restrict__ cls_sums4, float4* __restrict__ total4)
{
    const int col4 = blockIdx.x * 32 + (threadIdx.x & 31);
    const int cg   = threadIdx.x >> 5;   // 0..3, each sums 128 classes
    float4 s = make_float4(0.f, 0.f, 0.f, 0.f);
    for (int c = cg * 128; c < cg * 128 + 128; c += 4) {
        const float4 a = cls_sums4[(size_t)(c + 0) * D4 + col4];
        const float4 b = cls_sums4[(size_t)(c + 1) * D4 + col4];
        const float4 d = cls_sums4[(size_t)(c + 2) * D4 + col4];
        const float4 e = cls_sums4[(size_t)(c + 3) * D4 + col4];
        s.x += (a.x + b.x) + (d.x + e.x);
        s.y += (a.y + b.y) + (d.y + e.y);
        s.z += (a.z + b.z) + (d.z + e.z);
        s.w += (a.w + b.w) + (d.w + e.w);
    }
    __shared__ float4 red[128];
    red[threadIdx.x] = s;
    __syncthreads();
    if (threadIdx.x < 32) {
        float4 a = red[threadIdx.x];
        const float4 b = red[threadIdx.x + 32];
        const float4 d = red[threadIdx.x + 64];
        const float4 e = red[threadIdx.x + 96];
        a.x += (b.x + d.x) + e.x;
        a.y += (b.y + d.y) + e.y;
        a.z += (b.z + d.z) + e.z;
        a.w += (b.w + d.w) + e.w;
        total4[col4] = a;
    }
}

// ---------------- Kernel 6: per-class hinge, accumulate loss ----------------
__global__ __launch_bounds__(256)
void k_finalize(const float* __restrict__ cls_sums, const int* __restrict__ cnts,
                const float* __restrict__ total, float* __restrict__ d_out, int N)
{
    const int c   = blockIdx.x;
    const int tid = threadIdx.x;
    const int cnt = cnts[c];

    const float2 s = ((const float2*)cls_sums)[c * (DIM / 2) + tid];
    const float2 t = ((const float2*)total)[tid];

    float ss = 0.f;
    if (cnt > 0) {
        const float inv_c  = 1.f / (float)cnt;
        const float inv_nc = 1.f / (float)(N - cnt);
        const float d0 = s.x * inv_c - (t.x - s.x) * inv_nc + EPS;
        const float d1 = s.y * inv_c - (t.y - s.y) * inv_nc + EPS;
        ss = d0 * d0 + d1 * d1;
    }

    #pragma unroll
    for (int o = 1; o < 64; o <<= 1) ss += __shfl_xor(ss, o, 64);

    __shared__ float s_red[4];
    if ((tid & 63) == 0) s_red[tid >> 6] = ss;
    __syncthreads();

    if (tid == 0) {
        const float tot = (s_red[0] + s_red[1]) + (s_red[2] + s_red[3]);
        const float d = sqrtf(tot);
        const float w = fmaxf(MARGIN - d, 0.f);
        if (cnt > 0) atomicAdd(d_out, (float)cnt * w * w / (float)N);
    }
}

extern "C" void kernel_launch(void* const* d_in, const int* in_sizes, int n_in,
                              void* d_out, int out_size, void* d_ws, size_t ws_size,
                              hipStream_t stream)
{
    const float* x   = (const float*)d_in[0];
    const int*   lab = (const int*)d_in[1];
    float*       out = (float*)d_out;

    const int N = in_sizes[1];  // 65536 samples

    float* cls_sums = (float*)d_ws;                    // NCLS*DIM f32 = 1 MiB
    float* total    = cls_sums + (size_t)NCLS * DIM;   // DIM f32
    int*   cnts     = (int*)(total + DIM);             // NCLS
    int*   offsets  = cnts + NCLS;                     // NCLS
    int*   cur      = offsets + NCLS;                  // NCLS
    int*   sorted   = cur + NCLS;                      // N

    k_init<<<1, 512, 0, stream>>>(cnts);
    k_hist<<<64, 256, 0, stream>>>(lab, cnts, N);
    k_scan<<<1, 512, 0, stream>>>(cnts, offsets, cur, out);
    k_scatter<<<64, 256, 0, stream>>>(lab, cur, sorted, N);
    k_gather<<<NCLS, 512, 0, stream>>>((const float4*)x, sorted, offsets, cnts,
                                       (float4*)cls_sums);
    k_total<<<4, 128, 0, stream>>>((const float4*)cls_sums, (float4*)total);
    k_finalize<<<NCLS, 256, 0, stream>>>(cls_sums, cnts, total, out, N);
}